// Round 6
// baseline (147.284 us; speedup 1.0000x reference)
//
#include <hip/hip_runtime.h>

#define NN 50000
#define NE 250000
#define KTVC 4224        // 4 heads x (1024 ktv + 32 ksum)
#define NTILES 782       // ceil(NN/64)

__device__ __forceinline__ float lrelu(float x) { return x > 0.f ? x : 0.01f * x; }

// ---------------- kernel 0: zero the count buffers ----------------
__global__ __launch_bounds__(256) void k_zero(int* __restrict__ p) {
    int i = blockIdx.x * 256 + threadIdx.x;
    if (i < 100000) p[i] = 0;
}

// ---------------- kernel 1: histograms ----------------
__global__ __launch_bounds__(256) void k_hist(const int* __restrict__ src,
                                              const int* __restrict__ dst,
                                              int* __restrict__ cnt_src,
                                              int* __restrict__ cnt_dst) {
    int e = blockIdx.x * 256 + threadIdx.x;
    if (e < NE) {
        atomicAdd(&cnt_src[src[e]], 1);
        atomicAdd(&cnt_dst[dst[e]], 1);
    }
}

// ---------------- kernel 2: fc + LN + leaky ----------------
// 512 threads = 4 col-quarters x 128 nodes. Weights staged in LDS.
__global__ __launch_bounds__(512) void k_fc(const float* __restrict__ h,
                                            const float* __restrict__ Wfc,
                                            const float* __restrict__ bfc,
                                            const float* __restrict__ g1,
                                            const float* __restrict__ b1,
                                            float* __restrict__ resid,
                                            float* __restrict__ node33T) {
    __shared__ float wfc[129 * 32];    // 16.5 KB
    __shared__ float hch[128][33];     // 16.9 KB
    __shared__ float stat_t[8][128];
    __shared__ float stat2_t[4][128];
    const int tid = threadIdx.x;
    const int q = __builtin_amdgcn_readfirstlane((threadIdx.x >> 7) & 3);
    const int nl = tid & 127;
    const int base = blockIdx.x * 128;
    const int n = base + nl;

    for (int idx = tid; idx < 129 * 32; idx += 512) wfc[idx] = Wfc[idx];

    float acc[8];
#pragma unroll
    for (int jj = 0; jj < 8; ++jj) acc[jj] = bfc[q * 8 + jj];

    for (int c = 0; c < 4; ++c) {
        __syncthreads();
#pragma unroll
        for (int r = 0; r < 8; ++r) {
            int idx = r * 512 + tid;
            int sn = idx >> 5, t = idx & 31;
            int gn = base + sn;
            hch[sn][t] = h[(size_t)((gn < NN) ? gn : 0) * 128 + c * 32 + t];
        }
        __syncthreads();
#pragma unroll 8
        for (int i = 0; i < 32; ++i) {
            float hv = hch[nl][i];
            const float* wr = &wfc[(1 + c * 32 + i) * 32 + q * 8];
            float4 w0 = *(const float4*)&wr[0];
            float4 w1 = *(const float4*)&wr[4];
            acc[0] = fmaf(hv, w0.x, acc[0]); acc[1] = fmaf(hv, w0.y, acc[1]);
            acc[2] = fmaf(hv, w0.z, acc[2]); acc[3] = fmaf(hv, w0.w, acc[3]);
            acc[4] = fmaf(hv, w1.x, acc[4]); acc[5] = fmaf(hv, w1.y, acc[5]);
            acc[6] = fmaf(hv, w1.z, acc[6]); acc[7] = fmaf(hv, w1.w, acc[7]);
        }
    }
    // add row-0 (time-column) weights
    {
        const float* wr = &wfc[q * 8];
#pragma unroll
        for (int jj = 0; jj < 8; ++jj) acc[jj] += wr[jj];
    }
    float ps = 0.f, pq2 = 0.f;
#pragma unroll
    for (int jj = 0; jj < 8; ++jj) { ps += acc[jj]; pq2 += acc[jj] * acc[jj]; }
    stat_t[q * 2 + 0][nl] = ps;
    stat_t[q * 2 + 1][nl] = pq2;
    __syncthreads();
    float sm = stat_t[0][nl] + stat_t[2][nl] + stat_t[4][nl] + stat_t[6][nl];
    float sq = stat_t[1][nl] + stat_t[3][nl] + stat_t[5][nl] + stat_t[7][nl];
    float mean = sm * (1.f / 32.f);
    float var = fmaxf(sq * (1.f / 32.f) - mean * mean, 0.f);
    float rstd = rsqrtf(var + 1e-5f);
    float lr[8];
    float pl2 = 0.f;
#pragma unroll
    for (int jj = 0; jj < 8; ++jj) {
        int j = q * 8 + jj;
        float ln = (acc[jj] - mean) * rstd * g1[j] + b1[j];
        lr[jj] = lrelu(ln);
        pl2 += lr[jj] * lr[jj];
    }
    stat2_t[q][nl] = pl2;
    __syncthreads();
    float l2 = stat2_t[0][nl] + stat2_t[1][nl] + stat2_t[2][nl] + stat2_t[3][nl];
    if (n < NN) {
        float* rrow = resid + (size_t)n * 36;
#pragma unroll
        for (int jj = 0; jj < 8; ++jj) rrow[1 + q * 8 + jj] = acc[jj];
#pragma unroll
        for (int jj = 0; jj < 8; ++jj) node33T[(size_t)(1 + q * 8 + jj) * NN + n] = lr[jj];
        if (q == 0) {
            rrow[0] = sqrtf(sq + 1.f);
            node33T[n] = sqrtf(l2 + 1.f);
        }
    }
}

// ---------------- kernel 3: per-head k/v matvec + phi + register ktv partials ----------------
// grid (NTILES, 4 heads); block 128 = wave0 (k) + wave1 (v); lane = node.
// Weights staged in LDS (broadcast float4 reads); node vec in registers.
__global__ __launch_bounds__(128) void k_qkv(const float* __restrict__ node33T,
                                             const float* __restrict__ Wk, const float* __restrict__ bk,
                                             const float* __restrict__ Wv, const float* __restrict__ bv,
                                             const float* __restrict__ nscale,
                                             const int* __restrict__ cnt_src,
                                             float* __restrict__ partial) {
    __shared__ float wlds[2][1056];    // 8.4 KB
    __shared__ float pk[64][33];       // 8.4 KB
    __shared__ float pv[64][33];       // 8.4 KB
    const int tid = threadIdx.x;
    const int w_u = __builtin_amdgcn_readfirstlane(tid >> 6);   // 0 = k, 1 = v
    const int h_u = __builtin_amdgcn_readfirstlane(blockIdx.y);
    const int lane = tid & 63;
    const float inv = 1.f / fabsf(nscale[0]);
    const float* Wsrc = ((w_u == 0) ? Wk : Wv) + (size_t)h_u * 1056;
    const float* bb = ((w_u == 0) ? bk : bv) + h_u * 32;
    const int mm4 = lane >> 3, d4 = lane & 7;

    for (int idx = lane; idx < 1056; idx += 64) wlds[w_u][idx] = Wsrc[idx];

    const int base = blockIdx.x * 64;
    const int n = base + lane;
    const int nc = (n < NN) ? n : 0;

    float nvec[33];
#pragma unroll
    for (int c = 0; c < 33; ++c) nvec[c] = node33T[(size_t)c * NN + nc];

    float acc[32];
#pragma unroll
    for (int j = 0; j < 32; ++j) acc[j] = bb[j];
    __syncthreads();

#pragma unroll
    for (int i = 0; i < 33; ++i) {
        const float* wr = &wlds[w_u][i * 32];
#pragma unroll
        for (int j4 = 0; j4 < 8; ++j4) {
            float4 wv = *(const float4*)&wr[j4 * 4];
            acc[j4 * 4 + 0] = fmaf(nvec[i], wv.x, acc[j4 * 4 + 0]);
            acc[j4 * 4 + 1] = fmaf(nvec[i], wv.y, acc[j4 * 4 + 1]);
            acc[j4 * 4 + 2] = fmaf(nvec[i], wv.z, acc[j4 * 4 + 2]);
            acc[j4 * 4 + 3] = fmaf(nvec[i], wv.w, acc[j4 * 4 + 3]);
        }
    }

    if (w_u == 0) {
        const float wc = (n < NN) ? (float)cnt_src[n] : 0.f;
        float s2 = 0.f, s6 = 0.f;
#pragma unroll
        for (int j = 0; j < 32; ++j) {
            float x = (lrelu(acc[j]) + 1e-6f) * inv;
            s2 += x * x;
            float x3 = x * x * x;
            s6 += x3 * x3;
            acc[j] = x3;
        }
        const float factor = sqrtf(s2) / sqrtf(s6) * wc;
#pragma unroll
        for (int j = 0; j < 32; ++j) pk[lane][j] = factor * acc[j];
    } else {
#pragma unroll
        for (int j = 0; j < 32; ++j) pv[lane][j] = (lrelu(acc[j]) + 1e-6f) * inv;
    }
    __syncthreads();

    // ktv accumulate: wave0 nodes 0..31, wave1 nodes 32..63 (scalar broadcast reads).
    float facc[16];
#pragma unroll
    for (int t = 0; t < 16; ++t) facc[t] = 0.f;
    float ks[4] = {0.f, 0.f, 0.f, 0.f};
#pragma unroll 4
    for (int n0 = 0; n0 < 32; ++n0) {
        const int nn = w_u * 32 + n0;
        float pkv_a[4], pvv_a[4];
#pragma unroll
        for (int i = 0; i < 4; ++i) pkv_a[i] = pk[nn][mm4 * 4 + i];
#pragma unroll
        for (int i = 0; i < 4; ++i) pvv_a[i] = pv[nn][d4 * 4 + i];
#pragma unroll
        for (int i = 0; i < 4; ++i)
#pragma unroll
            for (int jj = 0; jj < 4; ++jj)
                facc[i * 4 + jj] = fmaf(pkv_a[i], pvv_a[jj], facc[i * 4 + jj]);
        if (d4 == 0) {
#pragma unroll
            for (int i = 0; i < 4; ++i) ks[i] += pkv_a[i];
        }
    }
    __syncthreads();

    // merge the two waves' partials through LDS scratch (wlds is dead now)
    float* scr = &wlds[0][0];      // 1056 floats available
    float* scr2 = &wlds[1][0];     // 32 floats
    if (w_u == 0) {
#pragma unroll
        for (int t = 0; t < 16; ++t) scr[lane * 16 + t] = facc[t];
        if (d4 == 0) {
#pragma unroll
            for (int i = 0; i < 4; ++i) scr2[mm4 * 4 + i] = ks[i];
        }
    }
    __syncthreads();
    if (w_u == 1) {
        float* pb = partial + (size_t)blockIdx.x * KTVC + h_u * 1056;
#pragma unroll
        for (int i = 0; i < 4; ++i)
#pragma unroll
            for (int jj = 0; jj < 4; ++jj)
                pb[(mm4 * 4 + i) * 32 + d4 * 4 + jj] =
                    facc[i * 4 + jj] + scr[lane * 16 + i * 4 + jj];
        if (d4 == 0) {
#pragma unroll
            for (int i = 0; i < 4; ++i)
                pb[1024 + mm4 * 4 + i] = ks[i] + scr2[mm4 * 4 + i];
        }
    }
}

// ---------------- kernel 4: parallel reduce of NTILES partial rows ----------------
__global__ __launch_bounds__(256) void k_red(const float* __restrict__ partial,
                                             float* __restrict__ ktvf) {
    __shared__ float red[8][33];
    const int tid = threadIdx.x;
    const int col = tid & 31, g = tid >> 5;
    const int c = blockIdx.x * 32 + col;
    const int r0 = g * 98, r1 = min(r0 + 98, NTILES);
    float s = 0.f;
    for (int r = r0; r < r1; ++r)
        s += partial[(size_t)r * KTVC + c];
    red[g][col] = s;
    __syncthreads();
    if (tid < 32) {
        float t0 = (red[0][tid] + red[1][tid]) + (red[2][tid] + red[3][tid]);
        float t1 = (red[4][tid] + red[5][tid]) + (red[6][tid] + red[7][tid]);
        ktvf[blockIdx.x * 32 + tid] = t0 + t1;
    }
}

// ---------------- kernel 5: q + phi_q + attention + edge_out + midpoint + LN2 ----------------
// 256 threads = 4 waves (one head each) x 64 nodes. Wq + ktv staged in LDS.
__global__ __launch_bounds__(256) void k_final(const float* __restrict__ node33T,
                                               const float* __restrict__ Wq, const float* __restrict__ bq,
                                               const float* __restrict__ nscale,
                                               const float* __restrict__ ktvf,
                                               const float* __restrict__ Who,
                                               const float* __restrict__ bho,
                                               const float* __restrict__ g2,
                                               const float* __restrict__ b2,
                                               const int* __restrict__ cnt_dst,
                                               const float* __restrict__ resid,
                                               float* __restrict__ out) {
    __shared__ float att[4][64][33];     // 33.8 KB
    __shared__ float wq_lds[4][1056];    // 16.9 KB
    __shared__ float ktv_l[4][1056];     // 16.9 KB
    __shared__ float who_lds[33 * 32];   //  4.2 KB
    __shared__ float g2l[32], b2l[32], bhol[32];
    const int tid = threadIdx.x;
    const int h_u = __builtin_amdgcn_readfirstlane(tid >> 6);
    const int lane = tid & 63;
    const int base = blockIdx.x * 64;
    const float inv = 1.f / fabsf(nscale[0]);
    const int n = base + lane;
    const int ncl = (n < NN) ? n : 0;

    for (int idx = lane; idx < 1056; idx += 64) {
        wq_lds[h_u][idx] = Wq[(size_t)h_u * 1056 + idx];
        ktv_l[h_u][idx] = ktvf[h_u * 1056 + idx];
    }
    for (int f = tid; f < 33 * 32; f += 256) who_lds[f] = Who[f];
    if (tid < 32) { g2l[tid] = g2[tid]; b2l[tid] = b2[tid]; bhol[tid] = bho[tid]; }

    float nvec[33];
#pragma unroll
    for (int c = 0; c < 33; ++c) nvec[c] = node33T[(size_t)c * NN + ncl];
    float acc[32];
#pragma unroll
    for (int j = 0; j < 32; ++j) acc[j] = bq[h_u * 32 + j];
    __syncthreads();

    // ---- phase A: per (node, head): q matvec + phi_q + num/den ----
    {
#pragma unroll
        for (int i = 0; i < 33; ++i) {
            const float* wr = &wq_lds[h_u][i * 32];
#pragma unroll
            for (int j4 = 0; j4 < 8; ++j4) {
                float4 wv = *(const float4*)&wr[j4 * 4];
                acc[j4 * 4 + 0] = fmaf(nvec[i], wv.x, acc[j4 * 4 + 0]);
                acc[j4 * 4 + 1] = fmaf(nvec[i], wv.y, acc[j4 * 4 + 1]);
                acc[j4 * 4 + 2] = fmaf(nvec[i], wv.z, acc[j4 * 4 + 2]);
                acc[j4 * 4 + 3] = fmaf(nvec[i], wv.w, acc[j4 * 4 + 3]);
            }
        }
        float s2 = 0.f, s6 = 0.f;
#pragma unroll
        for (int j = 0; j < 32; ++j) {
            float x = (lrelu(acc[j]) + 1e-6f) * inv;
            s2 += x * x;
            float x3 = x * x * x;
            s6 += x3 * x3;
            acc[j] = x3;
        }
        const float factor = sqrtf(s2) / sqrtf(s6);
        const float* ksum = &ktv_l[h_u][1024];
        float den = 0.f;
#pragma unroll
        for (int j = 0; j < 32; ++j) { acc[j] *= factor; den += acc[j] * ksum[j]; }
        const float rd = 0.25f / (den + 1e-6f);
        float num[32];
#pragma unroll
        for (int d = 0; d < 32; ++d) num[d] = 0.f;
#pragma unroll
        for (int t = 0; t < 32; ++t) {
            const float f = acc[t];
            const float* kr = &ktv_l[h_u][t * 32];
#pragma unroll
            for (int d4 = 0; d4 < 8; ++d4) {
                float4 kv = *(const float4*)&kr[d4 * 4];
                num[d4 * 4 + 0] = fmaf(f, kv.x, num[d4 * 4 + 0]);
                num[d4 * 4 + 1] = fmaf(f, kv.y, num[d4 * 4 + 1]);
                num[d4 * 4 + 2] = fmaf(f, kv.z, num[d4 * 4 + 2]);
                num[d4 * 4 + 3] = fmaf(f, kv.w, num[d4 * 4 + 3]);
            }
        }
#pragma unroll
        for (int d = 0; d < 32; ++d) att[h_u][lane][d] = num[d] * rd;
    }
    __syncthreads();

    // ---- phase B: per node (4 threads each, jq = quarter of output cols) ----
    const int nl2 = tid >> 2, jq = tid & 3;
    const int n2 = base + nl2;
    const int nc = (n2 < NN) ? n2 : NN - 1;
    float attn[32];
#pragma unroll
    for (int d = 0; d < 32; ++d)
        attn[d] = ((att[0][nl2][d] + att[1][nl2][d]) + (att[2][nl2][d] + att[3][nl2][d]));
    float a2 = 0.f;
#pragma unroll
    for (int d = 0; d < 32; ++d) a2 += attn[d] * attn[d];
    const float tc = sqrtf(a2 + 1.f);
    float eo[8];
#pragma unroll
    for (int jj = 0; jj < 8; ++jj) {
        int j = jq * 8 + jj;
        eo[jj] = bhol[j] + tc * who_lds[j];
    }
#pragma unroll
    for (int d = 0; d < 32; ++d) {
        const float f = attn[d];
        const float* wr = &who_lds[(1 + d) * 32 + jq * 8];
#pragma unroll
        for (int jj = 0; jj < 8; ++jj) eo[jj] = fmaf(f, wr[jj], eo[jj]);
    }
    float e2 = 0.f;
#pragma unroll
    for (int jj = 0; jj < 8; ++jj) e2 += eo[jj] * eo[jj];
    e2 += __shfl_xor(e2, 1);
    e2 += __shfl_xor(e2, 2);
    const float te = sqrtf(e2 + 1.f);
    const float sc = (cnt_dst[nc] > 0) ? 1.f : 0.f;
    const float* rr = resid + (size_t)nc * 36;
    const float av0 = 0.5f * (sc * te + rr[0]);
    float avs[8];
    float pinner = 0.f;
#pragma unroll
    for (int jj = 0; jj < 8; ++jj) {
        avs[jj] = 0.5f * (sc * eo[jj] + rr[1 + jq * 8 + jj]);
        pinner += avs[jj] * avs[jj];
    }
    pinner += __shfl_xor(pinner, 1);
    pinner += __shfl_xor(pinner, 2);
    const float inner = pinner - av0 * av0;
    const float rdn = 1.f / sqrtf(fmaxf(fabsf(inner), 1e-6f));
    float pm = 0.f;
#pragma unroll
    for (int jj = 0; jj < 8; ++jj) { avs[jj] *= rdn; pm += avs[jj]; }
    pm += __shfl_xor(pm, 1);
    pm += __shfl_xor(pm, 2);
    const float mean = pm * (1.f / 32.f);
    float pv2 = 0.f;
#pragma unroll
    for (int jj = 0; jj < 8; ++jj) { float dd = avs[jj] - mean; pv2 += dd * dd; }
    pv2 += __shfl_xor(pv2, 1);
    pv2 += __shfl_xor(pv2, 2);
    const float rstd = rsqrtf(pv2 * (1.f / 32.f) + 1e-5f);
    float ln[8];
    float pl2 = 0.f;
#pragma unroll
    for (int jj = 0; jj < 8; ++jj) {
        int j = jq * 8 + jj;
        ln[jj] = (avs[jj] - mean) * rstd * g2l[j] + b2l[j];
        pl2 += ln[jj] * ln[jj];
    }
    pl2 += __shfl_xor(pl2, 1);
    pl2 += __shfl_xor(pl2, 2);
    if (n2 < NN) {
        float* orow = out + (size_t)n2 * 33;
#pragma unroll
        for (int jj = 0; jj < 8; ++jj) orow[1 + jq * 8 + jj] = ln[jj];
        if (jq == 0) orow[0] = sqrtf(pl2 + 1.f);
    }
}

extern "C" void kernel_launch(void* const* d_in, const int* in_sizes, int n_in,
                              void* d_out, int out_size, void* d_ws, size_t ws_size,
                              hipStream_t stream) {
    const float* h   = (const float*)d_in[0];
    const int* src   = (const int*)d_in[1];
    const int* dst   = (const int*)d_in[2];
    const float* Wfc = (const float*)d_in[3];
    const float* bfc = (const float*)d_in[4];
    const float* g1  = (const float*)d_in[5];
    const float* b1  = (const float*)d_in[6];
    const float* Wq  = (const float*)d_in[7];
    const float* bq  = (const float*)d_in[8];
    const float* Wk  = (const float*)d_in[9];
    const float* bk  = (const float*)d_in[10];
    const float* Wv  = (const float*)d_in[11];
    const float* bv  = (const float*)d_in[12];
    const float* Who = (const float*)d_in[13];
    const float* bho = (const float*)d_in[14];
    const float* g2  = (const float*)d_in[15];
    const float* b2  = (const float*)d_in[16];
    const float* nsc = (const float*)d_in[17];
    float* out = (float*)d_out;
    char* ws = (char*)d_ws;

    int* cnt_src   = (int*)(ws + 0);           //  200,000 B
    int* cnt_dst   = (int*)(ws + 200000);      //  200,000 B
    float* resid   = (float*)(ws + 400000);    //  7.2 MB  [NN][36]
    float* node33T = (float*)(ws + 7600000);   //  6.6 MB  [33][NN]
    float* part    = (float*)(ws + 14200000);  // 13.2 MB  [NTILES][4224]
    float* ktvf    = (float*)(ws + 27412672);  // 16.9 KB

    hipLaunchKernelGGL(k_zero, dim3(391), dim3(256), 0, stream, (int*)ws);
    hipLaunchKernelGGL(k_hist, dim3((NE + 255) / 256), dim3(256), 0, stream,
                       src, dst, cnt_src, cnt_dst);
    hipLaunchKernelGGL(k_fc, dim3((NN + 127) / 128), dim3(512), 0, stream,
                       h, Wfc, bfc, g1, b1, resid, node33T);
    hipLaunchKernelGGL(k_qkv, dim3(NTILES, 4), dim3(128), 0, stream,
                       node33T, Wk, bk, Wv, bv, nsc, cnt_src, part);
    hipLaunchKernelGGL(k_red, dim3(KTVC / 32), dim3(256), 0, stream,
                       part, ktvf);
    hipLaunchKernelGGL(k_final, dim3((NN + 63) / 64), dim3(256), 0, stream,
                       node33T, Wq, bq, nsc, ktvf, Who, bho, g2, b2, cnt_dst, resid, out);
}

// Round 7
// 146.942 us; speedup vs baseline: 1.0023x; 1.0023x over previous
//
#include <hip/hip_runtime.h>

#define NN 50000
#define NE 250000
#define KTVC 4224        // 4 heads x (1024 ktv + 32 ksum)
#define NTILES 782       // ceil(NN/64)

__device__ __forceinline__ float lrelu(float x) { return x > 0.f ? x : 0.01f * x; }

// ---------------- kernel 0: zero the count buffers ----------------
__global__ __launch_bounds__(256) void k_zero(int* __restrict__ p) {
    int i = blockIdx.x * 256 + threadIdx.x;
    if (i < 100000) p[i] = 0;
}

// ---------------- kernel 1: histograms ----------------
__global__ __launch_bounds__(256) void k_hist(const int* __restrict__ src,
                                              const int* __restrict__ dst,
                                              int* __restrict__ cnt_src,
                                              int* __restrict__ cnt_dst) {
    int e = blockIdx.x * 256 + threadIdx.x;
    if (e < NE) {
        atomicAdd(&cnt_src[src[e]], 1);
        atomicAdd(&cnt_dst[dst[e]], 1);
    }
}

// ---------------- kernel 2: fc + LN + leaky (round-4 version) ----------------
// 512 threads = 4 col-quarters x 128 nodes. lane-per-node, s_load weights.
__global__ __launch_bounds__(512) void k_fc(const float* __restrict__ h,
                                            const float* __restrict__ Wfc,
                                            const float* __restrict__ bfc,
                                            const float* __restrict__ g1,
                                            const float* __restrict__ b1,
                                            float* __restrict__ resid,
                                            float* __restrict__ node33T) {
    __shared__ float hch[128][33];
    __shared__ float stat_t[8][128];
    __shared__ float stat2_t[4][128];
    const int tid = threadIdx.x;
    const int q = __builtin_amdgcn_readfirstlane((threadIdx.x >> 7) & 3);
    const int nl = tid & 127;
    const int base = blockIdx.x * 128;
    const int n = base + nl;

    float acc[8];
#pragma unroll
    for (int jj = 0; jj < 8; ++jj) acc[jj] = Wfc[q * 8 + jj] + bfc[q * 8 + jj];

    for (int c = 0; c < 4; ++c) {
        __syncthreads();
#pragma unroll
        for (int r = 0; r < 8; ++r) {
            int idx = r * 512 + tid;
            int sn = idx >> 5, t = idx & 31;
            int gn = base + sn;
            hch[sn][t] = h[(size_t)((gn < NN) ? gn : 0) * 128 + c * 32 + t];
        }
        __syncthreads();
        for (int i = 0; i < 32; ++i) {
            float hv = hch[nl][i];
            const float* wr = Wfc + (size_t)(1 + c * 32 + i) * 32 + q * 8;
#pragma unroll
            for (int jj = 0; jj < 8; ++jj) acc[jj] = fmaf(hv, wr[jj], acc[jj]);
        }
    }
    float ps = 0.f, pq2 = 0.f;
#pragma unroll
    for (int jj = 0; jj < 8; ++jj) { ps += acc[jj]; pq2 += acc[jj] * acc[jj]; }
    stat_t[q * 2 + 0][nl] = ps;
    stat_t[q * 2 + 1][nl] = pq2;
    __syncthreads();
    float sm = stat_t[0][nl] + stat_t[2][nl] + stat_t[4][nl] + stat_t[6][nl];
    float sq = stat_t[1][nl] + stat_t[3][nl] + stat_t[5][nl] + stat_t[7][nl];
    float mean = sm * (1.f / 32.f);
    float var = fmaxf(sq * (1.f / 32.f) - mean * mean, 0.f);
    float rstd = rsqrtf(var + 1e-5f);
    float lr[8];
    float pl2 = 0.f;
#pragma unroll
    for (int jj = 0; jj < 8; ++jj) {
        int j = q * 8 + jj;
        float ln = (acc[jj] - mean) * rstd * g1[j] + b1[j];
        lr[jj] = lrelu(ln);
        pl2 += lr[jj] * lr[jj];
    }
    stat2_t[q][nl] = pl2;
    __syncthreads();
    float l2 = stat2_t[0][nl] + stat2_t[1][nl] + stat2_t[2][nl] + stat2_t[3][nl];
    if (n < NN) {
        float* rrow = resid + (size_t)n * 36;
#pragma unroll
        for (int jj = 0; jj < 8; ++jj) rrow[1 + q * 8 + jj] = acc[jj];
#pragma unroll
        for (int jj = 0; jj < 8; ++jj) node33T[(size_t)(1 + q * 8 + jj) * NN + n] = lr[jj];
        if (q == 0) {
            rrow[0] = sqrtf(sq + 1.f);
            node33T[n] = sqrtf(l2 + 1.f);
        }
    }
}

// ---------------- kernel 3: per-head k/v matvec + phi + register ktv partials ----------------
// grid (NTILES, 4); block 128 = wave0 (k) + wave1 (v); lane = node of the 64-tile.
// LDS node staging, s_load weights (uniform pointer), stride-33 pk/pv (conflict-free).
__global__ __launch_bounds__(128) void k_qkv(const float* __restrict__ node33T,
                                             const float* __restrict__ Wk, const float* __restrict__ bk,
                                             const float* __restrict__ Wv, const float* __restrict__ bv,
                                             const float* __restrict__ nscale,
                                             const int* __restrict__ cnt_src,
                                             float* __restrict__ partial) {
    __shared__ float nlds[64][33];
    __shared__ float pk[64][33];
    __shared__ float pv[64][33];
    const int tid = threadIdx.x;
    const int w_u = __builtin_amdgcn_readfirstlane(tid >> 6);   // 0 = k, 1 = v
    const int h_u = __builtin_amdgcn_readfirstlane(blockIdx.y);
    const int lane = tid & 63;
    const float inv = 1.f / fabsf(nscale[0]);
    const float* W = ((w_u == 0) ? Wk : Wv) + (size_t)h_u * 1056;
    const float* bb = ((w_u == 0) ? bk : bv) + h_u * 32;
    const int mm4 = lane >> 3, d4 = lane & 7;
    const int base = blockIdx.x * 64;
    const int n = base + lane;

    // stage node vectors [64][33] from column-major global (coalesced per column)
    for (int idx = tid; idx < 2112; idx += 128) {
        int c = idx >> 6, sn = idx & 63;
        int gn = base + sn;
        nlds[sn][c] = node33T[(size_t)c * NN + ((gn < NN) ? gn : 0)];
    }
    __syncthreads();

    float acc[32];
#pragma unroll
    for (int j = 0; j < 32; ++j) acc[j] = bb[j];
    for (int i = 0; i < 33; ++i) {
        float hv = nlds[lane][i];
        const float* wr = W + (size_t)i * 32;
#pragma unroll
        for (int j = 0; j < 32; ++j) acc[j] = fmaf(hv, wr[j], acc[j]);
    }

    if (w_u == 0) {
        const float wc = (n < NN) ? (float)cnt_src[n] : 0.f;
        float s2 = 0.f, s6 = 0.f;
#pragma unroll
        for (int j = 0; j < 32; ++j) {
            float x = (lrelu(acc[j]) + 1e-6f) * inv;
            s2 += x * x;
            float x3 = x * x * x;
            s6 += x3 * x3;
            acc[j] = x3;
        }
        const float factor = sqrtf(s2) / sqrtf(s6) * wc;
#pragma unroll
        for (int j = 0; j < 32; ++j) pk[lane][j] = factor * acc[j];
    } else {
#pragma unroll
        for (int j = 0; j < 32; ++j) pv[lane][j] = (lrelu(acc[j]) + 1e-6f) * inv;
    }
    __syncthreads();

    // ktv accumulate: wave0 nodes 0..31, wave1 nodes 32..63.
    float facc[16];
#pragma unroll
    for (int t = 0; t < 16; ++t) facc[t] = 0.f;
    float ks[4] = {0.f, 0.f, 0.f, 0.f};
#pragma unroll 4
    for (int n0 = 0; n0 < 32; ++n0) {
        const int nn = w_u * 32 + n0;
        float pkv_a[4], pvv_a[4];
#pragma unroll
        for (int i = 0; i < 4; ++i) pkv_a[i] = pk[nn][mm4 * 4 + i];
#pragma unroll
        for (int i = 0; i < 4; ++i) pvv_a[i] = pv[nn][d4 * 4 + i];
#pragma unroll
        for (int i = 0; i < 4; ++i)
#pragma unroll
            for (int jj = 0; jj < 4; ++jj)
                facc[i * 4 + jj] = fmaf(pkv_a[i], pvv_a[jj], facc[i * 4 + jj]);
        if (d4 == 0) {
#pragma unroll
            for (int i = 0; i < 4; ++i) ks[i] += pkv_a[i];
        }
    }
    __syncthreads();

    // merge the two waves' partials through LDS scratch (nlds is dead now)
    float* scr = &nlds[0][0];          // 1024 floats
    float* scr2 = &nlds[0][0] + 1024;  // 32 floats
    if (w_u == 0) {
#pragma unroll
        for (int t = 0; t < 16; ++t) scr[lane * 16 + t] = facc[t];
        if (d4 == 0) {
#pragma unroll
            for (int i = 0; i < 4; ++i) scr2[mm4 * 4 + i] = ks[i];
        }
    }
    __syncthreads();
    if (w_u == 1) {
        float* pb = partial + (size_t)blockIdx.x * KTVC + h_u * 1056;
#pragma unroll
        for (int i = 0; i < 4; ++i)
#pragma unroll
            for (int jj = 0; jj < 4; ++jj)
                pb[(mm4 * 4 + i) * 32 + d4 * 4 + jj] =
                    facc[i * 4 + jj] + scr[lane * 16 + i * 4 + jj];
        if (d4 == 0) {
#pragma unroll
            for (int i = 0; i < 4; ++i)
                pb[1024 + mm4 * 4 + i] = ks[i] + scr2[mm4 * 4 + i];
        }
    }
}

// ---------------- kernel 4: parallel reduce of NTILES partial rows ----------------
__global__ __launch_bounds__(256) void k_red(const float* __restrict__ partial,
                                             float* __restrict__ ktvf) {
    __shared__ float red[8][33];
    const int tid = threadIdx.x;
    const int col = tid & 31, g = tid >> 5;
    const int c = blockIdx.x * 32 + col;
    const int r0 = g * 98, r1 = min(r0 + 98, NTILES);
    float s = 0.f;
    for (int r = r0; r < r1; ++r)
        s += partial[(size_t)r * KTVC + c];
    red[g][col] = s;
    __syncthreads();
    if (tid < 32) {
        float t0 = (red[0][tid] + red[1][tid]) + (red[2][tid] + red[3][tid]);
        float t1 = (red[4][tid] + red[5][tid]) + (red[6][tid] + red[7][tid]);
        ktvf[blockIdx.x * 32 + tid] = t0 + t1;
    }
}

// ---------------- kernel 5: q + phi_q + attention + edge_out + midpoint + LN2 ----------------
// (round-4 version) 256 threads = 4 waves (one head each) x 64 nodes.
__global__ __launch_bounds__(256) void k_final(const float* __restrict__ node33T,
                                               const float* __restrict__ Wq, const float* __restrict__ bq,
                                               const float* __restrict__ nscale,
                                               const float* __restrict__ ktvf,
                                               const float* __restrict__ Who,
                                               const float* __restrict__ bho,
                                               const float* __restrict__ g2,
                                               const float* __restrict__ b2,
                                               const int* __restrict__ cnt_dst,
                                               const float* __restrict__ resid,
                                               float* __restrict__ out) {
    __shared__ float nlds[64][37];
    __shared__ float att[4][64][33];
    __shared__ float who_lds[33 * 32];
    __shared__ float g2l[32], b2l[32], bhol[32];
    const int tid = threadIdx.x;
    const int h_u = __builtin_amdgcn_readfirstlane(tid >> 6);
    const int lane = tid & 63;
    const int base = blockIdx.x * 64;
    const float inv = 1.f / fabsf(nscale[0]);

#pragma unroll
    for (int r = 0; r < 9; ++r) {
        int idx = r * 256 + tid;
        if (idx < 2112) {
            int c = idx >> 6, sn = idx & 63;
            int gn = base + sn;
            nlds[sn][c] = node33T[(size_t)c * NN + ((gn < NN) ? gn : 0)];
        }
    }
    for (int f = tid; f < 33 * 32; f += 256) who_lds[f] = Who[f];
    if (tid < 32) { g2l[tid] = g2[tid]; b2l[tid] = b2[tid]; bhol[tid] = bho[tid]; }
    __syncthreads();

    // ---- phase A: per (node, head): q matvec + phi_q + num/den ----
    {
        float acc[32];
#pragma unroll
        for (int j = 0; j < 32; ++j) acc[j] = bq[h_u * 32 + j];
        const float* W = Wq + (size_t)h_u * 1056;
        for (int i = 0; i < 33; ++i) {
            float hv = nlds[lane][i];
            const float* wr = W + (size_t)i * 32;
#pragma unroll
            for (int j = 0; j < 32; ++j) acc[j] = fmaf(hv, wr[j], acc[j]);
        }
        float s2 = 0.f, s6 = 0.f;
#pragma unroll
        for (int j = 0; j < 32; ++j) {
            float x = (lrelu(acc[j]) + 1e-6f) * inv;
            s2 += x * x;
            float x3 = x * x * x;
            s6 += x3 * x3;
            acc[j] = x3;
        }
        const float factor = sqrtf(s2) / sqrtf(s6);
        const float* ksum = ktvf + h_u * 1056 + 1024;
        float den = 0.f;
#pragma unroll
        for (int j = 0; j < 32; ++j) { acc[j] *= factor; den += acc[j] * ksum[j]; }
        const float rd = 0.25f / (den + 1e-6f);
        float num[32];
#pragma unroll
        for (int d = 0; d < 32; ++d) num[d] = 0.f;
        const float* kt = ktvf + h_u * 1056;
#pragma unroll 2
        for (int t = 0; t < 32; ++t) {
            const float f = acc[t];
            const float* kr = kt + t * 32;
#pragma unroll
            for (int d = 0; d < 32; ++d) num[d] = fmaf(f, kr[d], num[d]);
        }
#pragma unroll
        for (int d = 0; d < 32; ++d) att[h_u][lane][d] = num[d] * rd;
    }
    __syncthreads();

    // ---- phase B: per node (4 threads each, jq = quarter of output cols) ----
    const int nl2 = tid >> 2, jq = tid & 3;
    const int n2 = base + nl2;
    const int nc = (n2 < NN) ? n2 : NN - 1;
    float attn[32];
#pragma unroll
    for (int d = 0; d < 32; ++d)
        attn[d] = ((att[0][nl2][d] + att[1][nl2][d]) + (att[2][nl2][d] + att[3][nl2][d]));
    float a2 = 0.f;
#pragma unroll
    for (int d = 0; d < 32; ++d) a2 += attn[d] * attn[d];
    const float tc = sqrtf(a2 + 1.f);
    float eo[8];
#pragma unroll
    for (int jj = 0; jj < 8; ++jj) {
        int j = jq * 8 + jj;
        eo[jj] = bhol[j] + tc * who_lds[j];
    }
#pragma unroll
    for (int d = 0; d < 32; ++d) {
        const float f = attn[d];
        const float* wr = &who_lds[(1 + d) * 32 + jq * 8];
#pragma unroll
        for (int jj = 0; jj < 8; ++jj) eo[jj] = fmaf(f, wr[jj], eo[jj]);
    }
    float e2 = 0.f;
#pragma unroll
    for (int jj = 0; jj < 8; ++jj) e2 += eo[jj] * eo[jj];
    e2 += __shfl_xor(e2, 1);
    e2 += __shfl_xor(e2, 2);
    const float te = sqrtf(e2 + 1.f);
    const float sc = (cnt_dst[nc] > 0) ? 1.f : 0.f;
    const float* rr = resid + (size_t)nc * 36;
    const float av0 = 0.5f * (sc * te + rr[0]);
    float avs[8];
    float pinner = 0.f;
#pragma unroll
    for (int jj = 0; jj < 8; ++jj) {
        avs[jj] = 0.5f * (sc * eo[jj] + rr[1 + jq * 8 + jj]);
        pinner += avs[jj] * avs[jj];
    }
    pinner += __shfl_xor(pinner, 1);
    pinner += __shfl_xor(pinner, 2);
    const float inner = pinner - av0 * av0;
    const float rdn = 1.f / sqrtf(fmaxf(fabsf(inner), 1e-6f));
    float pm = 0.f;
#pragma unroll
    for (int jj = 0; jj < 8; ++jj) { avs[jj] *= rdn; pm += avs[jj]; }
    pm += __shfl_xor(pm, 1);
    pm += __shfl_xor(pm, 2);
    const float mean = pm * (1.f / 32.f);
    float pv2 = 0.f;
#pragma unroll
    for (int jj = 0; jj < 8; ++jj) { float dd = avs[jj] - mean; pv2 += dd * dd; }
    pv2 += __shfl_xor(pv2, 1);
    pv2 += __shfl_xor(pv2, 2);
    const float rstd = rsqrtf(pv2 * (1.f / 32.f) + 1e-5f);
    float ln[8];
    float pl2 = 0.f;
#pragma unroll
    for (int jj = 0; jj < 8; ++jj) {
        int j = jq * 8 + jj;
        ln[jj] = (avs[jj] - mean) * rstd * g2l[j] + b2l[j];
        pl2 += ln[jj] * ln[jj];
    }
    pl2 += __shfl_xor(pl2, 1);
    pl2 += __shfl_xor(pl2, 2);
    if (n2 < NN) {
        float* orow = out + (size_t)n2 * 33;
#pragma unroll
        for (int jj = 0; jj < 8; ++jj) orow[1 + jq * 8 + jj] = ln[jj];
        if (jq == 0) orow[0] = sqrtf(pl2 + 1.f);
    }
}

extern "C" void kernel_launch(void* const* d_in, const int* in_sizes, int n_in,
                              void* d_out, int out_size, void* d_ws, size_t ws_size,
                              hipStream_t stream) {
    const float* h   = (const float*)d_in[0];
    const int* src   = (const int*)d_in[1];
    const int* dst   = (const int*)d_in[2];
    const float* Wfc = (const float*)d_in[3];
    const float* bfc = (const float*)d_in[4];
    const float* g1  = (const float*)d_in[5];
    const float* b1  = (const float*)d_in[6];
    const float* Wq  = (const float*)d_in[7];
    const float* bq  = (const float*)d_in[8];
    const float* Wk  = (const float*)d_in[9];
    const float* bk  = (const float*)d_in[10];
    const float* Wv  = (const float*)d_in[11];
    const float* bv  = (const float*)d_in[12];
    const float* Who = (const float*)d_in[13];
    const float* bho = (const float*)d_in[14];
    const float* g2  = (const float*)d_in[15];
    const float* b2  = (const float*)d_in[16];
    const float* nsc = (const float*)d_in[17];
    float* out = (float*)d_out;
    char* ws = (char*)d_ws;

    int* cnt_src   = (int*)(ws + 0);           //  200,000 B
    int* cnt_dst   = (int*)(ws + 200000);      //  200,000 B
    float* resid   = (float*)(ws + 400000);    //  7.2 MB  [NN][36]
    float* node33T = (float*)(ws + 7600000);   //  6.6 MB  [33][NN]
    float* part    = (float*)(ws + 14200000);  // 13.2 MB  [NTILES][4224]
    float* ktvf    = (float*)(ws + 27412672);  // 16.9 KB

    hipLaunchKernelGGL(k_zero, dim3(391), dim3(256), 0, stream, (int*)ws);
    hipLaunchKernelGGL(k_hist, dim3((NE + 255) / 256), dim3(256), 0, stream,
                       src, dst, cnt_src, cnt_dst);
    hipLaunchKernelGGL(k_fc, dim3((NN + 127) / 128), dim3(512), 0, stream,
                       h, Wfc, bfc, g1, b1, resid, node33T);
    hipLaunchKernelGGL(k_qkv, dim3(NTILES, 4), dim3(128), 0, stream,
                       node33T, Wk, bk, Wv, bv, nsc, cnt_src, part);
    hipLaunchKernelGGL(k_red, dim3(KTVC / 32), dim3(256), 0, stream,
                       part, ktvf);
    hipLaunchKernelGGL(k_final, dim3((NN + 63) / 64), dim3(256), 0, stream,
                       node33T, Wq, bq, nsc, ktvf, Who, bho, g2, b2, cnt_dst, resid, out);
}

// Round 8
// 127.628 us; speedup vs baseline: 1.1540x; 1.1513x over previous
//
#include <hip/hip_runtime.h>

#define NN 50000
#define NE 250000
#define KTVC 4224        // 4 heads x (1024 ktv + 32 ksum)
#define NBX 512          // tile-stride blocks per head for k_qkv

__device__ __forceinline__ float lrelu(float x) { return x > 0.f ? x : 0.01f * x; }

// ---------------- kernel 0: zero the count buffers (replaces hipMemsetAsync) ----------------
__global__ __launch_bounds__(256) void k_zero(int* __restrict__ p) {
    int i = blockIdx.x * 256 + threadIdx.x;
    if (i < 100000) p[i] = 0;
}

// ---------------- kernel 1: histograms ----------------
__global__ __launch_bounds__(256) void k_hist(const int* __restrict__ src,
                                              const int* __restrict__ dst,
                                              int* __restrict__ cnt_src,
                                              int* __restrict__ cnt_dst) {
    int e = blockIdx.x * 256 + threadIdx.x;
    if (e < NE) {
        atomicAdd(&cnt_src[src[e]], 1);
        atomicAdd(&cnt_dst[dst[e]], 1);
    }
}

// ---------------- kernel 2: fc + LN + leaky ----------------
// 512 threads = 4 col-quarters x 128 nodes. lane-per-node, scalar weights.
__global__ __launch_bounds__(512) void k_fc(const float* __restrict__ h,
                                            const float* __restrict__ Wfc,
                                            const float* __restrict__ bfc,
                                            const float* __restrict__ g1,
                                            const float* __restrict__ b1,
                                            float* __restrict__ resid,
                                            float* __restrict__ node33T) {
    __shared__ float hch[128][33];
    __shared__ float stat_t[8][128];
    __shared__ float stat2_t[4][128];
    const int tid = threadIdx.x;
    const int q = __builtin_amdgcn_readfirstlane((threadIdx.x >> 7) & 3);
    const int nl = tid & 127;
    const int base = blockIdx.x * 128;
    const int n = base + nl;

    float acc[8];
#pragma unroll
    for (int jj = 0; jj < 8; ++jj) acc[jj] = Wfc[q * 8 + jj] + bfc[q * 8 + jj];

    for (int c = 0; c < 4; ++c) {
        __syncthreads();
#pragma unroll
        for (int r = 0; r < 8; ++r) {
            int idx = r * 512 + tid;
            int sn = idx >> 5, t = idx & 31;
            int gn = base + sn;
            hch[sn][t] = h[(size_t)((gn < NN) ? gn : 0) * 128 + c * 32 + t];
        }
        __syncthreads();
        for (int i = 0; i < 32; ++i) {
            float hv = hch[nl][i];
            const float* wr = Wfc + (size_t)(1 + c * 32 + i) * 32 + q * 8;
#pragma unroll
            for (int jj = 0; jj < 8; ++jj) acc[jj] = fmaf(hv, wr[jj], acc[jj]);
        }
    }
    float ps = 0.f, pq2 = 0.f;
#pragma unroll
    for (int jj = 0; jj < 8; ++jj) { ps += acc[jj]; pq2 += acc[jj] * acc[jj]; }
    stat_t[q * 2 + 0][nl] = ps;
    stat_t[q * 2 + 1][nl] = pq2;
    __syncthreads();
    float sm = stat_t[0][nl] + stat_t[2][nl] + stat_t[4][nl] + stat_t[6][nl];
    float sq = stat_t[1][nl] + stat_t[3][nl] + stat_t[5][nl] + stat_t[7][nl];
    float mean = sm * (1.f / 32.f);
    float var = fmaxf(sq * (1.f / 32.f) - mean * mean, 0.f);
    float rstd = rsqrtf(var + 1e-5f);
    float lr[8];
    float pl2 = 0.f;
#pragma unroll
    for (int jj = 0; jj < 8; ++jj) {
        int j = q * 8 + jj;
        float ln = (acc[jj] - mean) * rstd * g1[j] + b1[j];
        lr[jj] = lrelu(ln);
        pl2 += lr[jj] * lr[jj];
    }
    stat2_t[q][nl] = pl2;
    __syncthreads();
    float l2 = stat2_t[0][nl] + stat2_t[1][nl] + stat2_t[2][nl] + stat2_t[3][nl];
    if (n < NN) {
        float* rrow = resid + (size_t)n * 36;
#pragma unroll
        for (int jj = 0; jj < 8; ++jj) rrow[1 + q * 8 + jj] = acc[jj];
#pragma unroll
        for (int jj = 0; jj < 8; ++jj) node33T[(size_t)(1 + q * 8 + jj) * NN + n] = lr[jj];
        if (q == 0) {
            rrow[0] = sqrtf(sq + 1.f);
            node33T[n] = sqrtf(l2 + 1.f);
        }
    }
}

// ---------------- kernel 3: per-head k/v matvec + phi + register ktv partials ----------------
// grid (NBX, 4 heads); block 128 = wave0 (k) + wave1 (v); lanes = 64 nodes of tile.
__global__ __launch_bounds__(128) void k_qkv(const float* __restrict__ node33T,
                                             const float* __restrict__ Wk, const float* __restrict__ bk,
                                             const float* __restrict__ Wv, const float* __restrict__ bv,
                                             const float* __restrict__ nscale,
                                             const int* __restrict__ cnt_src,
                                             float* __restrict__ partial) {
    __shared__ float nlds[64][33];
    __shared__ float pk[64][36];
    __shared__ float pv[64][36];
    const int tid = threadIdx.x;
    const int w_u = __builtin_amdgcn_readfirstlane(tid >> 6);   // 0 = k, 1 = v
    const int h_u = __builtin_amdgcn_readfirstlane(blockIdx.y);
    const int lane = tid & 63;
    const float inv = 1.f / fabsf(nscale[0]);
    const float* W = ((w_u == 0) ? Wk : Wv) + (size_t)h_u * 33 * 32;
    const float* bb = ((w_u == 0) ? bk : bv) + h_u * 32;
    const int mm4 = lane >> 3, d4 = lane & 7;

    float facc[16];
#pragma unroll
    for (int t = 0; t < 16; ++t) facc[t] = 0.f;
    float ks[4] = {0.f, 0.f, 0.f, 0.f};

    const int ntiles = (NN + 63) / 64;
    for (int tile = blockIdx.x; tile < ntiles; tile += NBX) {
        const int base = tile * 64;
        const int n = base + lane;
        // stage node vectors [64][33] from column-major global (coalesced per column)
        for (int idx = tid; idx < 2112; idx += 128) {
            int c = idx >> 6, sn = idx & 63;
            int gn = base + sn;
            nlds[sn][c] = node33T[(size_t)c * NN + ((gn < NN) ? gn : 0)];
        }
        __syncthreads();

        float acc[32];
#pragma unroll
        for (int j = 0; j < 32; ++j) acc[j] = bb[j];
        for (int i = 0; i < 33; ++i) {
            float hv = nlds[lane][i];
            const float* wr = W + (size_t)i * 32;
#pragma unroll
            for (int j = 0; j < 32; ++j) acc[j] = fmaf(hv, wr[j], acc[j]);
        }

        if (w_u == 0) {
            const float wc = (n < NN) ? (float)cnt_src[n] : 0.f;
            float s2 = 0.f, s6 = 0.f;
#pragma unroll
            for (int j = 0; j < 32; ++j) {
                float x = (lrelu(acc[j]) + 1e-6f) * inv;
                s2 += x * x;
                float x3 = x * x * x;
                s6 += x3 * x3;
                acc[j] = x3;
            }
            const float factor = sqrtf(s2) / sqrtf(s6) * wc;
#pragma unroll
            for (int j = 0; j < 32; ++j) pk[lane][j] = factor * acc[j];
        } else {
#pragma unroll
            for (int j = 0; j < 32; ++j) pv[lane][j] = (lrelu(acc[j]) + 1e-6f) * inv;
        }
        __syncthreads();

        // ktv accumulate: wave0 nodes 0..31, wave1 nodes 32..63 (head h_u).
#pragma unroll 4
        for (int n0 = 0; n0 < 32; ++n0) {
            const int nn = w_u * 32 + n0;
            float4 pkv = *(const float4*)&pk[nn][mm4 * 4];
            float4 pvv = *(const float4*)&pv[nn][d4 * 4];
            float pkv_a[4] = {pkv.x, pkv.y, pkv.z, pkv.w};
            float pvv_a[4] = {pvv.x, pvv.y, pvv.z, pvv.w};
#pragma unroll
            for (int i = 0; i < 4; ++i)
#pragma unroll
                for (int jj = 0; jj < 4; ++jj)
                    facc[i * 4 + jj] = fmaf(pkv_a[i], pvv_a[jj], facc[i * 4 + jj]);
            if (d4 == 0) {
#pragma unroll
                for (int i = 0; i < 4; ++i) ks[i] += pkv_a[i];
            }
        }
        __syncthreads();   // pk/pv reads done before next tile's overwrite
    }

    // merge the two waves' partials through LDS scratch (pk/pv are dead now)
    float* scr = &pk[0][0];      // 1024 floats
    float* scr2 = &pv[0][0];     // 32 floats
    if (w_u == 0) {
#pragma unroll
        for (int t = 0; t < 16; ++t) scr[lane * 16 + t] = facc[t];
        if (d4 == 0) {
#pragma unroll
            for (int i = 0; i < 4; ++i) scr2[mm4 * 4 + i] = ks[i];
        }
    }
    __syncthreads();
    if (w_u == 1) {
        float* pb = partial + (size_t)blockIdx.x * KTVC + h_u * 1056;
#pragma unroll
        for (int i = 0; i < 4; ++i)
#pragma unroll
            for (int jj = 0; jj < 4; ++jj)
                pb[(mm4 * 4 + i) * 32 + d4 * 4 + jj] =
                    facc[i * 4 + jj] + scr[lane * 16 + i * 4 + jj];
        if (d4 == 0) {
#pragma unroll
            for (int i = 0; i < 4; ++i)
                pb[1024 + mm4 * 4 + i] = ks[i] + scr2[mm4 * 4 + i];
        }
    }
}

// ---------------- kernel 4: parallel reduce of NBX partial rows ----------------
__global__ __launch_bounds__(256) void k_red(const float* __restrict__ partial,
                                             float* __restrict__ ktvf) {
    __shared__ float red[8][33];
    const int tid = threadIdx.x;
    const int col = tid & 31, g = tid >> 5;
    const int c = blockIdx.x * 32 + col;
    float s = 0.f;
    for (int r = g * 64; r < (g + 1) * 64; ++r)
        s += partial[(size_t)r * KTVC + c];
    red[g][col] = s;
    __syncthreads();
    if (tid < 32) {
        float t0 = (red[0][tid] + red[1][tid]) + (red[2][tid] + red[3][tid]);
        float t1 = (red[4][tid] + red[5][tid]) + (red[6][tid] + red[7][tid]);
        ktvf[blockIdx.x * 32 + tid] = t0 + t1;
    }
}

// ---------------- kernel 5: q + phi_q + attention + edge_out + midpoint + LN2 ----------------
// 256 threads = 4 waves (one head each) x 64 nodes.
__global__ __launch_bounds__(256) void k_final(const float* __restrict__ node33T,
                                               const float* __restrict__ Wq, const float* __restrict__ bq,
                                               const float* __restrict__ nscale,
                                               const float* __restrict__ ktvf,
                                               const float* __restrict__ Who,
                                               const float* __restrict__ bho,
                                               const float* __restrict__ g2,
                                               const float* __restrict__ b2,
                                               const int* __restrict__ cnt_dst,
                                               const float* __restrict__ resid,
                                               float* __restrict__ out) {
    __shared__ float nlds[64][37];
    __shared__ float att[4][64][33];
    __shared__ float who_lds[33 * 32];
    __shared__ float g2l[32], b2l[32], bhol[32];
    const int tid = threadIdx.x;
    const int h_u = __builtin_amdgcn_readfirstlane(tid >> 6);
    const int lane = tid & 63;
    const int base = blockIdx.x * 64;
    const float inv = 1.f / fabsf(nscale[0]);

#pragma unroll
    for (int r = 0; r < 9; ++r) {
        int idx = r * 256 + tid;
        if (idx < 2112) {
            int c = idx >> 6, sn = idx & 63;
            int gn = base + sn;
            nlds[sn][c] = node33T[(size_t)c * NN + ((gn < NN) ? gn : 0)];
        }
    }
    for (int f = tid; f < 33 * 32; f += 256) who_lds[f] = Who[f];
    if (tid < 32) { g2l[tid] = g2[tid]; b2l[tid] = b2[tid]; bhol[tid] = bho[tid]; }
    __syncthreads();

    // ---- phase A: per (node, head): q matvec + phi_q + num/den ----
    {
        float acc[32];
#pragma unroll
        for (int j = 0; j < 32; ++j) acc[j] = bq[h_u * 32 + j];
        const float* W = Wq + (size_t)h_u * 33 * 32;
        for (int i = 0; i < 33; ++i) {
            float hv = nlds[lane][i];
            const float* wr = W + (size_t)i * 32;
#pragma unroll
            for (int j = 0; j < 32; ++j) acc[j] = fmaf(hv, wr[j], acc[j]);
        }
        float s2 = 0.f, s6 = 0.f;
#pragma unroll
        for (int j = 0; j < 32; ++j) {
            float x = (lrelu(acc[j]) + 1e-6f) * inv;
            s2 += x * x;
            float x3 = x * x * x;
            s6 += x3 * x3;
            acc[j] = x3;
        }
        const float factor = sqrtf(s2) / sqrtf(s6);
        const float* ksum = ktvf + h_u * 1056 + 1024;
        float den = 0.f;
#pragma unroll
        for (int j = 0; j < 32; ++j) { acc[j] *= factor; den += acc[j] * ksum[j]; }
        const float rd = 0.25f / (den + 1e-6f);
        float num[32];
#pragma unroll
        for (int d = 0; d < 32; ++d) num[d] = 0.f;
        const float* kt = ktvf + h_u * 1056;
#pragma unroll 2
        for (int t = 0; t < 32; ++t) {
            const float f = acc[t];
            const float* kr = kt + t * 32;
#pragma unroll
            for (int d = 0; d < 32; ++d) num[d] = fmaf(f, kr[d], num[d]);
        }
#pragma unroll
        for (int d = 0; d < 32; ++d) att[h_u][lane][d] = num[d] * rd;
    }
    __syncthreads();

    // ---- phase B: per node (4 threads each, jq = quarter of output cols) ----
    const int nl2 = tid >> 2, jq = tid & 3;
    const int n2 = base + nl2;
    const int nc = (n2 < NN) ? n2 : NN - 1;
    float attn[32];
#pragma unroll
    for (int d = 0; d < 32; ++d)
        attn[d] = ((att[0][nl2][d] + att[1][nl2][d]) + (att[2][nl2][d] + att[3][nl2][d]));
    float a2 = 0.f;
#pragma unroll
    for (int d = 0; d < 32; ++d) a2 += attn[d] * attn[d];
    const float tc = sqrtf(a2 + 1.f);
    float eo[8];
#pragma unroll
    for (int jj = 0; jj < 8; ++jj) {
        int j = jq * 8 + jj;
        eo[jj] = bhol[j] + tc * who_lds[j];
    }
#pragma unroll
    for (int d = 0; d < 32; ++d) {
        const float f = attn[d];
        const float* wr = &who_lds[(1 + d) * 32 + jq * 8];
#pragma unroll
        for (int jj = 0; jj < 8; ++jj) eo[jj] = fmaf(f, wr[jj], eo[jj]);
    }
    float e2 = 0.f;
#pragma unroll
    for (int jj = 0; jj < 8; ++jj) e2 += eo[jj] * eo[jj];
    e2 += __shfl_xor(e2, 1);
    e2 += __shfl_xor(e2, 2);
    const float te = sqrtf(e2 + 1.f);
    const float sc = (cnt_dst[nc] > 0) ? 1.f : 0.f;
    const float* rr = resid + (size_t)nc * 36;
    const float av0 = 0.5f * (sc * te + rr[0]);
    float avs[8];
    float pinner = 0.f;
#pragma unroll
    for (int jj = 0; jj < 8; ++jj) {
        avs[jj] = 0.5f * (sc * eo[jj] + rr[1 + jq * 8 + jj]);
        pinner += avs[jj] * avs[jj];
    }
    pinner += __shfl_xor(pinner, 1);
    pinner += __shfl_xor(pinner, 2);
    const float inner = pinner - av0 * av0;
    const float rdn = 1.f / sqrtf(fmaxf(fabsf(inner), 1e-6f));
    float pm = 0.f;
#pragma unroll
    for (int jj = 0; jj < 8; ++jj) { avs[jj] *= rdn; pm += avs[jj]; }
    pm += __shfl_xor(pm, 1);
    pm += __shfl_xor(pm, 2);
    const float mean = pm * (1.f / 32.f);
    float pv2 = 0.f;
#pragma unroll
    for (int jj = 0; jj < 8; ++jj) { float dd = avs[jj] - mean; pv2 += dd * dd; }
    pv2 += __shfl_xor(pv2, 1);
    pv2 += __shfl_xor(pv2, 2);
    const float rstd = rsqrtf(pv2 * (1.f / 32.f) + 1e-5f);
    float ln[8];
    float pl2 = 0.f;
#pragma unroll
    for (int jj = 0; jj < 8; ++jj) {
        int j = jq * 8 + jj;
        ln[jj] = (avs[jj] - mean) * rstd * g2l[j] + b2l[j];
        pl2 += ln[jj] * ln[jj];
    }
    pl2 += __shfl_xor(pl2, 1);
    pl2 += __shfl_xor(pl2, 2);
    if (n2 < NN) {
        float* orow = out + (size_t)n2 * 33;
#pragma unroll
        for (int jj = 0; jj < 8; ++jj) orow[1 + jq * 8 + jj] = ln[jj];
        if (jq == 0) orow[0] = sqrtf(pl2 + 1.f);
    }
}

extern "C" void kernel_launch(void* const* d_in, const int* in_sizes, int n_in,
                              void* d_out, int out_size, void* d_ws, size_t ws_size,
                              hipStream_t stream) {
    const float* h   = (const float*)d_in[0];
    const int* src   = (const int*)d_in[1];
    const int* dst   = (const int*)d_in[2];
    const float* Wfc = (const float*)d_in[3];
    const float* bfc = (const float*)d_in[4];
    const float* g1  = (const float*)d_in[5];
    const float* b1  = (const float*)d_in[6];
    const float* Wq  = (const float*)d_in[7];
    const float* bq  = (const float*)d_in[8];
    const float* Wk  = (const float*)d_in[9];
    const float* bk  = (const float*)d_in[10];
    const float* Wv  = (const float*)d_in[11];
    const float* bv  = (const float*)d_in[12];
    const float* Who = (const float*)d_in[13];
    const float* bho = (const float*)d_in[14];
    const float* g2  = (const float*)d_in[15];
    const float* b2  = (const float*)d_in[16];
    const float* nsc = (const float*)d_in[17];
    float* out = (float*)d_out;
    char* ws = (char*)d_ws;

    int* cnt_src   = (int*)(ws + 0);           //  200,000 B
    int* cnt_dst   = (int*)(ws + 200000);      //  200,000 B
    float* resid   = (float*)(ws + 400000);    //  7.2 MB  [NN][36]
    float* node33T = (float*)(ws + 7600000);   //  6.6 MB  [33][NN]
    float* part    = (float*)(ws + 14200000);  //  8.65 MB [NBX][4224]
    float* ktvf    = (float*)(ws + 22852608);  //  16.9 KB

    hipLaunchKernelGGL(k_zero, dim3(391), dim3(256), 0, stream, (int*)ws);
    hipLaunchKernelGGL(k_hist, dim3((NE + 255) / 256), dim3(256), 0, stream,
                       src, dst, cnt_src, cnt_dst);
    hipLaunchKernelGGL(k_fc, dim3((NN + 127) / 128), dim3(512), 0, stream,
                       h, Wfc, bfc, g1, b1, resid, node33T);
    hipLaunchKernelGGL(k_qkv, dim3(NBX, 4), dim3(128), 0, stream,
                       node33T, Wk, bk, Wv, bv, nsc, cnt_src, part);
    hipLaunchKernelGGL(k_red, dim3(KTVC / 32), dim3(256), 0, stream,
                       part, ktvf);
    hipLaunchKernelGGL(k_final, dim3((NN + 63) / 64), dim3(256), 0, stream,
                       node33T, Wq, bq, nsc, ktvf, Who, bho, g2, b2, cnt_dst, resid, out);
}